// Round 9
// baseline (185.259 us; speedup 1.0000x reference)
//
#include <hip/hip_runtime.h>
#include <hip/hip_bf16.h>
#include <stdint.h>

// Problem: N=512, R=4, B=65536, OUT=512
// out = relu(x @ W + b1) @ W2 + b2,  W = krylov_recon(G,H) (512x512)

typedef __attribute__((ext_vector_type(8))) short bf16x8;   // MFMA A/B frag (4 VGPR)
typedef __attribute__((ext_vector_type(4))) float f32x4;    // MFMA C/D frag
typedef __attribute__((ext_vector_type(4))) unsigned int u32x4;

__device__ __forceinline__ unsigned short f2bf(float f) {
  return __builtin_bit_cast(unsigned short, __float2bfloat16(f));
}

// ---------------------------------------------------------------------------
// Kernel 1: W partials.  W[a,b] = sum_i sum_j G[(a-j)&511,i]*sgn(b+j)*H[(b+j)&511,i]
// ---------------------------------------------------------------------------
__global__ void build_w_partials(const float* __restrict__ G, const float* __restrict__ H,
                                 float* __restrict__ Wp) {
  __shared__ float4 Gs[512];
  __shared__ float4 Hs[512];
  const int t = threadIdx.x;  // 256
  const float4* G4 = (const float4*)G;
  const float4* H4 = (const float4*)H;
  for (int i = t; i < 512; i += 256) { Gs[i] = G4[i]; Hs[i] = H4[i]; }
  __syncthreads();

  const int blk  = blockIdx.x;      // 0..255
  const int tile = blk >> 2;
  const int jc   = blk & 3;
  const int a0 = (tile >> 3) << 6;
  const int b0 = (tile & 7) << 6;
  const int ab = a0 + ((t >> 4) << 2);
  const int bb = b0 + ((t & 15) << 2);

  float acc[4][4] = {};
  const int j0 = jc << 7;
  for (int jj = 0; jj < 128; ++jj) {
    const int j = j0 + jj;
    float4 Ga[4], Hb[4];
#pragma unroll
    for (int r = 0; r < 4; ++r) Ga[r] = Gs[(ab + r - j) & 511];
#pragma unroll
    for (int c = 0; c < 4; ++c) {
      const int idx = bb + c + j;
      const float s = (idx >= 512) ? -1.f : 1.f;
      const float4 hv = Hs[idx & 511];
      Hb[c].x = hv.x * s; Hb[c].y = hv.y * s; Hb[c].z = hv.z * s; Hb[c].w = hv.w * s;
    }
#pragma unroll
    for (int r = 0; r < 4; ++r)
#pragma unroll
      for (int c = 0; c < 4; ++c)
        acc[r][c] += Ga[r].x * Hb[c].x + Ga[r].y * Hb[c].y +
                     Ga[r].z * Hb[c].z + Ga[r].w * Hb[c].w;
  }

  float* outp = Wp + (size_t)jc * 262144;
#pragma unroll
  for (int r = 0; r < 4; ++r)
#pragma unroll
    for (int c = 0; c < 4; ++c)
      outp[(size_t)(ab + r) * 512 + (bb + c)] = acc[r][c];
}

// ---------------------------------------------------------------------------
// Kernel 2: reduce 4 partials, store W transposed bf16: Wt[n=b][k=a]
// ---------------------------------------------------------------------------
__global__ void reduce_transpose_w(const float* __restrict__ Wp, unsigned short* __restrict__ Wt) {
  const int idx = blockIdx.x * 256 + threadIdx.x;
  const int b = idx >> 9, a = idx & 511;
  const size_t o = (size_t)a * 512 + b;
  float s = Wp[o] + Wp[o + 262144] + Wp[o + 524288] + Wp[o + 786432];
  Wt[(size_t)b * 512 + a] = f2bf(s);
}

// ---------------------------------------------------------------------------
// Kernel 3: W2 (512x512 f32 [k][n]) -> W2t bf16 [n][k]
// ---------------------------------------------------------------------------
__global__ void transpose_convert_w2(const float* __restrict__ W2, unsigned short* __restrict__ W2t) {
  const int idx = blockIdx.x * 256 + threadIdx.x;
  const int n = idx >> 9, k = idx & 511;
  W2t[(size_t)n * 512 + k] = f2bf(W2[(size_t)k * 512 + n]);
}

// ---------------------------------------------------------------------------
// m97-replica GEMM: C[M x 512] = epi(A[M x 512] @ Bt^T + bias)
// 128x128 tile, 256 threads (4 waves 2x2, per-wave 64x64 = 4x4 frags),
// BK=32, NT=16, double-buffered LDS, ONE __syncthreads per K-tile
// (compiler-managed waitcnts -- m97 regime), 3 blocks/CU:
//   AF32 (GEMM1, A=x f32): LDS 2 x (16K A + 8K B) = 48KB; cvt_pk in-reg.
//   bf16 (GEMM2, A=h):     LDS 2 x ( 8K A + 8K B) = 32KB.
// __launch_bounds__(256,3) caps regs at ~170 (acc 4x4 in AGPR).
// Swizzles carried verbatim from r6-r8 (correctness-proven):
//   f32 rows (128B):  byte = r*128 + ((c ^ (r&7))<<4)
//   bf16 rows (64B):  byte = r*64  + ((c ^ ((r>>1)&3))<<4)
// gll = linear LDS dest + inverse-permuted global source (rule 21).
// ---------------------------------------------------------------------------
template <bool AF32>
__global__ __launch_bounds__(256, 3) void gemm_m97(
    const void* __restrict__ Ap, const unsigned short* __restrict__ Bt,
    const float* __restrict__ bias, void* __restrict__ Cp) {
  constexpr int NT    = 16;
  constexpr int ASLOT = AF32 ? 16384 : 8192;   // 128 x 32 x {4,2}B
  constexpr int BSLOT = 8192;                  // 128 x 32 x 2B
  constexpr int BUF   = ASLOT + BSLOT;         // 24K / 16K
  constexpr int NAG   = AF32 ? 4 : 2;          // A glls / thread / tile

  __shared__ __attribute__((aligned(16))) char lds[2 * BUF];   // 48K / 32K

  const int tid  = threadIdx.x;
  const int lane = tid & 63;
  const int w    = tid >> 6;          // 0..3
  const int wm   = w & 1;             // M half (64 rows)
  const int wn   = w >> 1;            // N half (64 cols)
  const int lr   = lane & 15;
  const int lq   = lane >> 4;

  const int bid = (int)blockIdx.x;                 // 2048 blocks
  const int wg  = (bid & 7) * 256 + (bid >> 3);    // XCD-bijective (2048%8==0)
  const int m0  = (wg >> 2) << 7;                  // 512 M-tiles
  const int n0  = (wg & 3) << 7;                   // 4 N-tiles

  float bv[4];
#pragma unroll
  for (int ni = 0; ni < 4; ++ni) bv[ni] = bias[n0 + wn * 64 + ni * 16 + lr];

  // ---- staging source byte offsets (inverse-permuted per 16B chunk) ----
  size_t aSrcOff[NAG];
  if constexpr (AF32) {
#pragma unroll
    for (int i = 0; i < 4; ++i) {
      const int cl = i * 256 + tid;                // chunk 0..1023
      const int r = cl >> 3, d = cl & 7;
      aSrcOff[i] = (size_t)r * 2048 + (size_t)((d ^ (r & 7)) << 4);
    }
  } else {
#pragma unroll
    for (int i = 0; i < 2; ++i) {
      const int cl = i * 256 + tid;                // chunk 0..511
      const int r = cl >> 2, d = cl & 3;
      aSrcOff[i] = (size_t)r * 1024 + (size_t)((d ^ ((r >> 1) & 3)) << 4);
    }
  }
  size_t bSrcOff[2];
#pragma unroll
  for (int i = 0; i < 2; ++i) {
    const int cl = i * 256 + tid;
    const int r = cl >> 2, d = cl & 3;
    bSrcOff[i] = (size_t)r * 1024 + (size_t)((d ^ ((r >> 1) & 3)) << 4);
  }
  const char* aBase = (const char*)Ap + (size_t)m0 * (AF32 ? 2048 : 1024);
  const char* bBase = (const char*)Bt + (size_t)n0 * 1024;

  auto stage = [&](int kt, int buf) {
    char* sb = lds + buf * BUF;
#pragma unroll
    for (int i = 0; i < NAG; ++i)
      __builtin_amdgcn_global_load_lds(
        (const __attribute__((address_space(1))) void*)
          (aBase + aSrcOff[i] + (size_t)kt * (AF32 ? 128 : 64)),
        (__attribute__((address_space(3))) void*)(sb + i * 4096 + w * 1024),
        16, 0, 0);
#pragma unroll
    for (int i = 0; i < 2; ++i)
      __builtin_amdgcn_global_load_lds(
        (const __attribute__((address_space(1))) void*)
          (bBase + bSrcOff[i] + (size_t)kt * 64),
        (__attribute__((address_space(3))) void*)(sb + ASLOT + i * 4096 + w * 1024),
        16, 0, 0);
  };

  // ---- frag ds_read offsets (conflict-free per consecutive-8 lanes) ----
  int offA[4], offB[4];
#pragma unroll
  for (int mi = 0; mi < 4; ++mi) {
    const int r = wm * 64 + mi * 16 + lr;
    if constexpr (AF32)
      offA[mi] = r * 128 + (((2 * lq) ^ (r & 7)) << 4);    // hi read = ^16
    else
      offA[mi] = r * 64 + ((lq ^ ((r >> 1) & 3)) << 4);
  }
#pragma unroll
  for (int ni = 0; ni < 4; ++ni) {
    const int rb = wn * 64 + ni * 16 + lr;
    offB[ni] = ASLOT + rb * 64 + ((lq ^ ((rb >> 1) & 3)) << 4);
  }

  f32x4 acc[4][4];
  const f32x4 vz = {0.f, 0.f, 0.f, 0.f};
#pragma unroll
  for (int i = 0; i < 4; ++i)
#pragma unroll
    for (int j = 0; j < 4; ++j) acc[i][j] = vz;

  // ---- prologue: stage tile 0; __syncthreads drains vmcnt (m97 pattern) ----
  stage(0, 0);
  __syncthreads();

#pragma unroll
  for (int t = 0; t < NT; ++t) {
    const int cur = t & 1;
    if (t < NT - 1) stage(t + 1, cur ^ 1);   // issue next-tile loads first

    const char* sb = lds + cur * BUF;
    bf16x8 bfr[4];
#pragma unroll
    for (int ni = 0; ni < 4; ++ni) bfr[ni] = *(const bf16x8*)(sb + offB[ni]);

    if constexpr (AF32) {
      // process mi in pairs to bound register pressure (lo/hi reused)
#pragma unroll
      for (int g = 0; g < 2; ++g) {
        f32x4 lo[2], hi[2];
        bf16x8 afr[2];
#pragma unroll
        for (int p = 0; p < 2; ++p) {
          lo[p] = *(const f32x4*)(sb + offA[2 * g + p]);
          hi[p] = *(const f32x4*)(sb + (offA[2 * g + p] ^ 16));
        }
#pragma unroll
        for (int p = 0; p < 2; ++p) {
          unsigned int w0, w1, w2, w3;   // RNE f32->bf16 pack
          asm("v_cvt_pk_bf16_f32 %0, %1, %2" : "=v"(w0) : "v"(lo[p].x), "v"(lo[p].y));
          asm("v_cvt_pk_bf16_f32 %0, %1, %2" : "=v"(w1) : "v"(lo[p].z), "v"(lo[p].w));
          asm("v_cvt_pk_bf16_f32 %0, %1, %2" : "=v"(w2) : "v"(hi[p].x), "v"(hi[p].y));
          asm("v_cvt_pk_bf16_f32 %0, %1, %2" : "=v"(w3) : "v"(hi[p].z), "v"(hi[p].w));
          u32x4 pw = {w0, w1, w2, w3};
          afr[p] = __builtin_bit_cast(bf16x8, pw);
        }
#pragma unroll
        for (int p = 0; p < 2; ++p)
#pragma unroll
          for (int ni = 0; ni < 4; ++ni)
            acc[2 * g + p][ni] =
                __builtin_amdgcn_mfma_f32_16x16x32_bf16(afr[p], bfr[ni], acc[2 * g + p][ni], 0, 0, 0);
      }
    } else {
      bf16x8 afr[4];
#pragma unroll
      for (int mi = 0; mi < 4; ++mi) afr[mi] = *(const bf16x8*)(sb + offA[mi]);
#pragma unroll
      for (int mi = 0; mi < 4; ++mi)
#pragma unroll
        for (int ni = 0; ni < 4; ++ni)
          acc[mi][ni] = __builtin_amdgcn_mfma_f32_16x16x32_bf16(afr[mi], bfr[ni], acc[mi][ni], 0, 0, 0);
    }

    __syncthreads();   // drains this wave's stage(t+1) glls + all ds ops
  }

  // ---- epilogue: C/D col=lr, row=lq*4+i ----
#pragma unroll
  for (int ni = 0; ni < 4; ++ni) {
    const int gc = n0 + wn * 64 + ni * 16 + lr;
#pragma unroll
    for (int mi = 0; mi < 4; ++mi) {
      const int gr = m0 + wm * 64 + mi * 16 + lq * 4;
      const f32x4 v = acc[mi][ni];
#pragma unroll
      for (int i = 0; i < 4; ++i) {
        const float val = v[i] + bv[ni];
        if constexpr (AF32)
          ((unsigned short*)Cp)[(size_t)(gr + i) * 512 + gc] = f2bf(val > 0.f ? val : 0.f);
        else
          ((float*)Cp)[(size_t)(gr + i) * 512 + gc] = val;
      }
    }
  }
}

// ---------------------------------------------------------------------------
extern "C" void kernel_launch(void* const* d_in, const int* in_sizes, int n_in,
                              void* d_out, int out_size, void* d_ws, size_t ws_size,
                              hipStream_t stream) {
  (void)in_sizes; (void)n_in; (void)out_size; (void)ws_size;
  const float* x  = (const float*)d_in[0];  // (65536, 512)
  const float* G  = (const float*)d_in[1];  // (512, 4)
  const float* H  = (const float*)d_in[2];  // (512, 4)
  const float* b1 = (const float*)d_in[3];  // (512,)
  const float* W2 = (const float*)d_in[4];  // (512, 512)
  const float* b2 = (const float*)d_in[5];  // (512,)
  float* out = (float*)d_out;               // (65536, 512) f32

  char* ws = (char*)d_ws;                                    // ~72.4 MB
  unsigned short* h   = (unsigned short*)ws;                 // 67,108,864 B
  unsigned short* Wt  = (unsigned short*)(ws + 67108864);    //    524,288 B
  unsigned short* W2t = (unsigned short*)(ws + 67633152);    //    524,288 B
  float*          Wp  = (float*)(ws + 68157440);             //  4,194,304 B

  build_w_partials<<<256, 256, 0, stream>>>(G, H, Wp);
  reduce_transpose_w<<<1024, 256, 0, stream>>>(Wp, Wt);
  transpose_convert_w2<<<1024, 256, 0, stream>>>(W2, W2t);
  gemm_m97<true><<<2048, 256, 0, stream>>>((const void*)x, Wt, b1, (void*)h);
  gemm_m97<false><<<2048, 256, 0, stream>>>((const void*)h, W2t, b2, (void*)out);
}